// Round 3
// baseline (263.442 us; speedup 1.0000x reference)
//
#include <hip/hip_runtime.h>
#include <hip/hip_bf16.h>
#include <string.h>

#define NB   2
#define SEQ  2048
#define EMB  1024
#define NH   16
#define HD   64
// softmax uses exp2: fold SCALE*log2(e) into Q pre-scale and the mask table
#define QSCALE 0.045084219f       // (1/32) * log2(e)
#define MADD2  -4.5084219e18f     // -1e20 * (1/32) * log2(e)

typedef __attribute__((ext_vector_type(8))) short short8;   // 8 x bf16
typedef __attribute__((ext_vector_type(4))) float f32x4;    // MFMA C/D

#define MFMA(a, b, c) __builtin_amdgcn_mfma_f32_16x16x32_bf16(a, b, c, 0, 0, 0)
#define EXP2(x) __builtin_amdgcn_exp2f(x)

__device__ __forceinline__ unsigned short f2bf(float x) {
    union { float f; unsigned u; } v; v.f = x;
    unsigned r = v.u + 0x7fffu + ((v.u >> 16) & 1u);   // RNE
    return (unsigned short)(r >> 16);
}
__device__ __forceinline__ unsigned packbf2(float a, float b) {
    __hip_bfloat162 h = __float22bfloat162_rn(make_float2(a, b));  // hw v_cvt_pk
    unsigned u; memcpy(&u, &h, 4);
    return u;
}

// ---------------------------------------------------------------------------
// Kernel 0: convert Wo/Wq/Wk/Wv fp32->bf16, build exp2-domain madd table.
// ---------------------------------------------------------------------------
__global__ __launch_bounds__(256) void cvt_kernel(
    const float* __restrict__ Wo, const float* __restrict__ Wq,
    const float* __restrict__ Wk, const float* __restrict__ Wv,
    const int* __restrict__ mask,
    unsigned short* __restrict__ Wob, unsigned short* __restrict__ Wqb,
    unsigned short* __restrict__ Wkb, unsigned short* __restrict__ Wvb,
    float* __restrict__ maddG)
{
    const int b = blockIdx.x, tid = threadIdx.x;
    if (b < 1024) {                       // Wo: 262144 float4
        int idx = b * 256 + tid;
        float4 w = ((const float4*)Wo)[idx];
        uint2 p; p.x = packbf2(w.x, w.y); p.y = packbf2(w.z, w.w);
        ((uint2*)Wob)[idx] = p;
    } else if (b < 1027) {                // Wq/Wk/Wv: 1024 float4 each
        const float* W = (b == 1024) ? Wq : (b == 1025) ? Wk : Wv;
        unsigned short* Wb = (b == 1024) ? Wqb : (b == 1025) ? Wkb : Wvb;
        #pragma unroll
        for (int i = 0; i < 4; ++i) {
            int idx = tid + i * 256;
            float4 w = ((const float4*)W)[idx];
            uint2 p; p.x = packbf2(w.x, w.y); p.y = packbf2(w.z, w.w);
            ((uint2*)Wb)[idx] = p;
        }
    } else {                              // madd: NB*SEQ = 4096 entries
        #pragma unroll
        for (int i = 0; i < 16; ++i) {
            int idx = tid + i * 256;
            maddG[idx] = mask[idx] ? 0.f : MADD2;
        }
    }
}

// ---------------------------------------------------------------------------
// Kernel 1: per-head QKV projection.  grid (SEQ/128, NH, 3*NB), block 256.
// Q,K out: [n][h][l][d] bf16 (Q pre-scaled by QSCALE).  V out: [n][h][d][l].
// ---------------------------------------------------------------------------
__global__ __launch_bounds__(256) void qkv_kernel(
    const float* __restrict__ Qin, const float* __restrict__ Kin,
    const float* __restrict__ Vin,
    const unsigned short* __restrict__ Wqb, const unsigned short* __restrict__ Wkb,
    const unsigned short* __restrict__ Wvb, const float* __restrict__ bq,
    unsigned short* __restrict__ Qp, unsigned short* __restrict__ Kp,
    unsigned short* __restrict__ Vtp)
{
    const int lt = blockIdx.x;          // 128-row l tile
    const int h  = blockIdx.y;
    const int tz = blockIdx.z;
    const int t  = tz >> 1, n = tz & 1;

    const float* X; const unsigned short* Wb;
    if (t == 0)      { X = Qin; Wb = Wqb; }
    else if (t == 1) { X = Kin; Wb = Wkb; }
    else             { X = Vin; Wb = Wvb; }

    __shared__ __align__(16) unsigned short sX[128][70];
    __shared__ __align__(16) unsigned short sT[64][136];

    const int tid = threadIdx.x, wave = tid >> 6, lane = tid & 63;
    const int ln = lane & 15, quad = lane >> 4;

    #pragma unroll
    for (int i = 0; i < 8; ++i) {
        int flat = tid + i * 256;
        int r = flat >> 4, c4 = flat & 15;
        float4 xv = *(const float4*)(X + ((size_t)(n * SEQ + lt * 128 + r)) * EMB + h * HD + c4 * 4);
        uint2 xp; xp.x = packbf2(xv.x, xv.y); xp.y = packbf2(xv.z, xv.w);
        *(uint2*)&sX[r][c4 * 4] = xp;
    }
    short8 wf0[4], wf1[4];
    #pragma unroll
    for (int nt = 0; nt < 4; ++nt) {
        wf0[nt] = *(const short8*)(Wb + (nt * 16 + ln) * HD + quad * 8);
        wf1[nt] = *(const short8*)(Wb + (nt * 16 + ln) * HD + 32 + quad * 8);
    }
    __syncthreads();

    f32x4 acc[2][4];
    #pragma unroll
    for (int set = 0; set < 2; ++set) {
        short8 af0 = *(const short8*)&sX[wave * 32 + set * 16 + ln][quad * 8];
        short8 af1 = *(const short8*)&sX[wave * 32 + set * 16 + ln][32 + quad * 8];
        #pragma unroll
        for (int nt = 0; nt < 4; ++nt) {
            f32x4 a = {0.f, 0.f, 0.f, 0.f};
            a = MFMA(af0, wf0[nt], a);
            a = MFMA(af1, wf1[nt], a);
            acc[set][nt] = a;
        }
    }

    if (t == 0) {   // bias then fold softmax scale (incl. log2e)
        #pragma unroll
        for (int nt = 0; nt < 4; ++nt) {
            float bb = bq[nt * 16 + ln];
            #pragma unroll
            for (int set = 0; set < 2; ++set)
                #pragma unroll
                for (int a = 0; a < 4; ++a)
                    acc[set][nt][a] = (acc[set][nt][a] + bb) * QSCALE;
        }
    }

    if (t < 2) {
        unsigned short* Out = (t == 0) ? Qp : Kp;
        #pragma unroll
        for (int set = 0; set < 2; ++set)
            #pragma unroll
            for (int a = 0; a < 4; ++a) {
                size_t row = (size_t)((n * NH + h) * SEQ + lt * 128 + wave * 32 + set * 16 + quad * 4 + a);
                #pragma unroll
                for (int nt = 0; nt < 4; ++nt)
                    Out[row * HD + nt * 16 + ln] = f2bf(acc[set][nt][a]);
            }
    } else {
        #pragma unroll
        for (int set = 0; set < 2; ++set)
            #pragma unroll
            for (int nt = 0; nt < 4; ++nt)
                #pragma unroll
                for (int a = 0; a < 4; ++a)
                    sT[nt * 16 + ln][wave * 32 + set * 16 + quad * 4 + a] = f2bf(acc[set][nt][a]);
        __syncthreads();
        #pragma unroll
        for (int i = 0; i < 4; ++i) {
            int flat = tid + i * 256;
            int r = flat >> 4, c8 = flat & 15;
            *(float4*)(Vtp + ((size_t)((n * NH + h) * HD + r)) * SEQ + lt * 128 + c8 * 8) =
                *(const float4*)&sT[r][c8 * 8];
        }
    }
}

// ---------------------------------------------------------------------------
// Kernel 2: flash attention v8 — register-footprint fix for real occupancy.
// History:
//   v5 (2 waves/blk, 64q): 82 us.  v6 ((256,4) forced): spill, 333 us.
//   v7 ((256,2), 4 waves/blk, 64q): spill gone but occupancy STILL 19% and
//   94 us.  Root cause: unified VGPR+AGPR file — reported VGPR 124 excludes
//   the o[4][4] accumulator (64 AGPR); true footprint ~188 -> hard 2
//   waves/SIMD cap regardless of grid/block shape.
// v8: per-wave tile halved so TOTAL regs fit 128 -> 4 waves/SIMD:
//   - 32 q-rows per block (grid.y = SEQ/32 = 64), 2 waves, each wave takes
//     half the keys (16 k-tiles).  o[2][4]=32 AGPR, qf[2][2]=16 VGPR.
//   - V fragments loaded AFTER the QK/softmax phase (short live range, -24
//     live regs); latency covered by 4-waves/SIMD TLP, V is L2-hot.
//   - __launch_bounds__(128,4): unified cap 128, natural alloc ~116 -> no
//     spill (v6's mistake was forcing 128 on a ~188-reg body).
//   LDS 9.2 KB/block -> 8 blocks/CU; grid 2048 blocks = 8/CU; 16 waves/CU.
//   Total MFMA/exp2 work unchanged; K/V L2 traffic 2x (still << L2 ceiling),
//   nh-fastest grid keeps heads XCD-pinned.
// grid (NB*NH, SEQ/32), block 128 (2 waves).
// ---------------------------------------------------------------------------
__global__ __launch_bounds__(128, 4) void flash_kernel(
    const unsigned short* __restrict__ Qp, const unsigned short* __restrict__ Kp,
    const unsigned short* __restrict__ Vtp, const float* __restrict__ maddG,
    unsigned short* __restrict__ A /* [n][l][EMB] bf16 */)
{
    const int nh = blockIdx.x;
    const int qt = blockIdx.y;            // 32-row q tile
    const int n  = nh >> 4, h = nh & 15;

    const int tid  = threadIdx.x;
    const int wave = tid >> 6, lane = tid & 63;
    const int ln   = lane & 15, quad = lane >> 4;

    __shared__ __align__(16) unsigned short sP[2][32][72];   // 9,216 B: per-wave P slices
    // epilogue exchange overlays sP (dead after the K-loop):
    // xO[32][65] f32 (8,320 B) + xl[32] f32 (128 B) = 8,448 B <= 9,216 B
    float (*xO)[65] = reinterpret_cast<float(*)[65]>(&sP[0][0][0]);
    float* xl = reinterpret_cast<float*>(reinterpret_cast<char*>(&sP[0][0][0]) + 32 * 65 * 4);

    // Q B-fragments for 2 row-sets (Q pre-scaled by QSCALE)
    const unsigned short* Qb = Qp + ((size_t)nh * SEQ + qt * 32) * HD;
    short8 qf[2][2];
    #pragma unroll
    for (int set = 0; set < 2; ++set) {
        qf[set][0] = *(const short8*)(Qb + (set * 16 + ln) * HD + quad * 8);
        qf[set][1] = *(const short8*)(Qb + (set * 16 + ln) * HD + 32 + quad * 8);
    }

    const unsigned short* Kb = Kp  + (size_t)nh * SEQ * HD;
    const unsigned short* Vb = Vtp + (size_t)nh * HD * SEQ;
    const float* mb = maddG + n * SEQ;

    f32x4 o[2][4];
    #pragma unroll
    for (int s2 = 0; s2 < 2; ++s2)
        #pragma unroll
        for (int dt = 0; dt < 4; ++dt) o[s2][dt] = (f32x4){0.f, 0.f, 0.f, 0.f};
    float lsum[2] = {0.f, 0.f};

    const int kt0 = wave * (SEQ / 64 / 2);          // 2-way in-block key split
    for (int kt = kt0; kt < kt0 + SEQ / 64 / 2; ++kt) {
        #pragma unroll
        for (int nt = 0; nt < 4; ++nt) {
            // K A-fragments direct from global
            const unsigned short* kr = Kb + (size_t)(kt * 64 + nt * 16 + ln) * HD;
            short8 kf0 = *(const short8*)(kr + quad * 8);
            short8 kf1 = *(const short8*)(kr + 32 + quad * 8);
            float4 md  = *(const float4*)(mb + kt * 64 + nt * 16 + quad * 4);

            #pragma unroll
            for (int set = 0; set < 2; ++set) {
                f32x4 z = {0.f, 0.f, 0.f, 0.f};
                z = MFMA(kf0, qf[set][0], z);
                z = MFMA(kf1, qf[set][1], z);
                // S^T C-layout: (key = nt*16+quad*4+a, q = set*16+ln)
                float p0 = EXP2(fminf(z[0] + md.x, 80.f));
                float p1 = EXP2(fminf(z[1] + md.y, 80.f));
                float p2 = EXP2(fminf(z[2] + md.z, 80.f));
                float p3 = EXP2(fminf(z[3] + md.w, 80.f));
                lsum[set] += (p0 + p1) + (p2 + p3);
                uint2 w; w.x = packbf2(p0, p1); w.y = packbf2(p2, p3);
                *(uint2*)&sP[wave][set * 16 + ln][nt * 16 + quad * 4] = w;
            }
        }

        // V B-fragments: issued here (post-QK) to keep their live range short;
        // 4-waves/SIMD TLP + L2-hot V covers the latency.
        short8 vf[4][2];
        #pragma unroll
        for (int dt = 0; dt < 4; ++dt) {
            const unsigned short* vr = Vb + (size_t)(dt * 16 + ln) * SEQ + kt * 64;
            vf[dt][0] = *(const short8*)(vr + quad * 8);
            vf[dt][1] = *(const short8*)(vr + 32 + quad * 8);
        }

        asm volatile("s_waitcnt lgkmcnt(0)" ::: "memory");   // per-wave slice

        // ---- O += P V ----
        #pragma unroll
        for (int set = 0; set < 2; ++set) {
            short8 pf0 = *(const short8*)&sP[wave][set * 16 + ln][quad * 8];
            short8 pf1 = *(const short8*)&sP[wave][set * 16 + ln][32 + quad * 8];
            #pragma unroll
            for (int dt = 0; dt < 4; ++dt) {
                o[set][dt] = MFMA(pf0, vf[dt][0], o[set][dt]);
                o[set][dt] = MFMA(pf1, vf[dt][1], o[set][dt]);
            }
        }
    }

    // ---- reduce l over quads (all lanes get this wave's sum for q = set*16+ln) ----
    float lf[2];
    #pragma unroll
    for (int set = 0; set < 2; ++set) {
        float l = lsum[set];
        l += __shfl_xor(l, 16);
        l += __shfl_xor(l, 32);
        lf[set] = l;
    }

    // ---- in-block combine of the two key-halves ----
    __syncthreads();                      // both waves done with sP
    if (wave == 1) {
        #pragma unroll
        for (int set = 0; set < 2; ++set) {
            #pragma unroll
            for (int a = 0; a < 4; ++a)
                #pragma unroll
                for (int dt = 0; dt < 4; ++dt)
                    xO[set * 16 + quad * 4 + a][dt * 16 + ln] = o[set][dt][a];
            if (quad == 0) xl[set * 16 + ln] = lf[set];
        }
    }
    __syncthreads();
    if (wave == 0) {
        #pragma unroll
        for (int set = 0; set < 2; ++set)
            #pragma unroll
            for (int a = 0; a < 4; ++a) {
                int q = set * 16 + quad * 4 + a;
                float l0 = __shfl(lf[set], q & 15);        // this wave's l at q
                float inv = 1.0f / (l0 + xl[q]);
                size_t row = (size_t)(n * SEQ + qt * 32 + q);
                #pragma unroll
                for (int dt = 0; dt < 4; ++dt)
                    A[row * EMB + h * HD + dt * 16 + ln] =
                        f2bf((o[set][dt][a] + xO[q][dt * 16 + ln]) * inv);
            }
    }
}

// ---------------------------------------------------------------------------
// Kernel 3: out = A @ Wo^T + bo, 128x128 tile (m93 structure).
// grid (EMB/128, NB*SEQ/128), block 256 (2x2 waves of 64x64).
// ---------------------------------------------------------------------------
__global__ __launch_bounds__(256) void outproj_kernel(
    const unsigned short* __restrict__ A, const unsigned short* __restrict__ Wob,
    const float* __restrict__ bo, float* __restrict__ Out)
{
    const int ct = blockIdx.x;   // 128-col tile
    const int rt = blockIdx.y;   // 128-row tile

    const int tid  = threadIdx.x;
    const int wave = tid >> 6, lane = tid & 63;
    const int ln   = lane & 15, quad = lane >> 4;
    const int wm   = wave >> 1, wn = wave & 1;

    __shared__ __align__(16) unsigned short sA[128][72];
    __shared__ __align__(16) unsigned short sB[128][72];

    f32x4 acc[4][4];
    #pragma unroll
    for (int i = 0; i < 4; ++i)
        #pragma unroll
        for (int j = 0; j < 4; ++j) acc[i][j] = (f32x4){0.f, 0.f, 0.f, 0.f};

    for (int kc = 0; kc < EMB / 64; ++kc) {
        __syncthreads();
        #pragma unroll
        for (int i = 0; i < 4; ++i) {
            int flat = tid + i * 256;          // 0..1023, 8-bf16 groups
            int r = flat >> 3, c8 = flat & 7;
            *(float4*)&sA[r][c8 * 8] =
                *(const float4*)(A + (size_t)(rt * 128 + r) * EMB + kc * 64 + c8 * 8);
            *(float4*)&sB[r][c8 * 8] =
                *(const float4*)(Wob + (size_t)(ct * 128 + r) * EMB + kc * 64 + c8 * 8);
        }
        __syncthreads();

        #pragma unroll
        for (int ks = 0; ks < 2; ++ks) {
            short8 af[4], bf[4];
            #pragma unroll
            for (int i = 0; i < 4; ++i)
                af[i] = *(const short8*)&sA[wm * 64 + i * 16 + ln][ks * 32 + quad * 8];
            #pragma unroll
            for (int j = 0; j < 4; ++j)
                bf[j] = *(const short8*)&sB[wn * 64 + j * 16 + ln][ks * 32 + quad * 8];
            #pragma unroll
            for (int i = 0; i < 4; ++i)
                #pragma unroll
                for (int j = 0; j < 4; ++j)
                    acc[i][j] = MFMA(af[i], bf[j], acc[i][j]);
        }
    }

    #pragma unroll
    for (int j = 0; j < 4; ++j) {
        int col = ct * 128 + wn * 64 + j * 16 + ln;
        float bb = bo[col];
        #pragma unroll
        for (int i = 0; i < 4; ++i)
            #pragma unroll
            for (int a = 0; a < 4; ++a) {
                size_t row = (size_t)(rt * 128 + wm * 64 + i * 16 + quad * 4 + a);
                Out[row * EMB + col] = acc[i][j][a] + bb;
            }
    }
}

// ---------------------------------------------------------------------------
extern "C" void kernel_launch(void* const* d_in, const int* in_sizes, int n_in,
                              void* d_out, int out_size, void* d_ws, size_t ws_size,
                              hipStream_t stream) {
    const float* values = (const float*)d_in[0];
    const float* key_   = (const float*)d_in[1];
    const float* query  = (const float*)d_in[2];
    const int*   mask   = (const int*)d_in[3];
    const float* Wv     = (const float*)d_in[4];
    const float* Wk     = (const float*)d_in[5];
    const float* Wq     = (const float*)d_in[6];
    const float* bq     = (const float*)d_in[7];
    const float* Wo     = (const float*)d_in[8];
    const float* bo     = (const float*)d_in[9];
    float* out = (float*)d_out;

    const size_t NHLD = (size_t)NB * NH * SEQ * HD;   // 4,194,304

    unsigned short* ws = (unsigned short*)d_ws;
    unsigned short* Qp    = ws;
    unsigned short* Kp    = ws + NHLD;
    unsigned short* Vtp   = ws + 2 * NHLD;
    unsigned short* Aattn = ws + 3 * NHLD;
    unsigned short* Wob   = ws + 4 * NHLD;                  // EMB*EMB
    unsigned short* Wqb   = Wob + (size_t)EMB * EMB;
    unsigned short* Wkb   = Wqb + HD * HD;
    unsigned short* Wvb   = Wkb + HD * HD;
    float* maddG = (float*)(Wvb + HD * HD);                 // NB*SEQ floats

    cvt_kernel<<<dim3(1028), 256, 0, stream>>>(
        Wo, Wq, Wk, Wv, mask, Wob, Wqb, Wkb, Wvb, maddG);
    qkv_kernel<<<dim3(SEQ / 128, NH, 3 * NB), 256, 0, stream>>>(
        query, key_, values, Wqb, Wkb, Wvb, bq, Qp, Kp, Vtp);
    flash_kernel<<<dim3(NB * NH, SEQ / 32), 128, 0, stream>>>(
        Qp, Kp, Vtp, maddG, Aattn);
    outproj_kernel<<<dim3(EMB / 128, NB * SEQ / 128), 256, 0, stream>>>(
        Aattn, Wob, bo, out);
}

// Round 4
// 205.092 us; speedup vs baseline: 1.2845x; 1.2845x over previous
//
#include <hip/hip_runtime.h>
#include <hip/hip_bf16.h>
#include <string.h>

#define NB   2
#define SEQ  2048
#define EMB  1024
#define NH   16
#define HD   64
// softmax uses exp2: fold SCALE*log2(e) into Q pre-scale and the mask table
#define QSCALE 0.045084219f       // (1/32) * log2(e)
#define MADD2  -4.5084219e18f     // -1e20 * (1/32) * log2(e)

typedef __attribute__((ext_vector_type(8))) short short8;   // 8 x bf16
typedef __attribute__((ext_vector_type(4))) float f32x4;    // MFMA C/D

#define MFMA(a, b, c) __builtin_amdgcn_mfma_f32_16x16x32_bf16(a, b, c, 0, 0, 0)
#define EXP2(x) __builtin_amdgcn_exp2f(x)

__device__ __forceinline__ unsigned short f2bf(float x) {
    union { float f; unsigned u; } v; v.f = x;
    unsigned r = v.u + 0x7fffu + ((v.u >> 16) & 1u);   // RNE
    return (unsigned short)(r >> 16);
}
__device__ __forceinline__ unsigned packbf2(float a, float b) {
    __hip_bfloat162 h = __float22bfloat162_rn(make_float2(a, b));  // hw v_cvt_pk
    unsigned u; memcpy(&u, &h, 4);
    return u;
}
// async global->LDS, 16B per lane; LDS dest = uniform base + lane*16 (linear)
__device__ __forceinline__ void gload16(const void* g, void* l) {
    __builtin_amdgcn_global_load_lds(
        (const __attribute__((address_space(1))) void*)g,
        (__attribute__((address_space(3))) void*)l, 16, 0, 0);
}

// ---------------------------------------------------------------------------
// Kernel 0: convert Wo/Wq/Wk/Wv fp32->bf16, build exp2-domain madd table.
// ---------------------------------------------------------------------------
__global__ __launch_bounds__(256) void cvt_kernel(
    const float* __restrict__ Wo, const float* __restrict__ Wq,
    const float* __restrict__ Wk, const float* __restrict__ Wv,
    const int* __restrict__ mask,
    unsigned short* __restrict__ Wob, unsigned short* __restrict__ Wqb,
    unsigned short* __restrict__ Wkb, unsigned short* __restrict__ Wvb,
    float* __restrict__ maddG)
{
    const int b = blockIdx.x, tid = threadIdx.x;
    if (b < 1024) {                       // Wo: 262144 float4
        int idx = b * 256 + tid;
        float4 w = ((const float4*)Wo)[idx];
        uint2 p; p.x = packbf2(w.x, w.y); p.y = packbf2(w.z, w.w);
        ((uint2*)Wob)[idx] = p;
    } else if (b < 1027) {                // Wq/Wk/Wv: 1024 float4 each
        const float* W = (b == 1024) ? Wq : (b == 1025) ? Wk : Wv;
        unsigned short* Wb = (b == 1024) ? Wqb : (b == 1025) ? Wkb : Wvb;
        #pragma unroll
        for (int i = 0; i < 4; ++i) {
            int idx = tid + i * 256;
            float4 w = ((const float4*)W)[idx];
            uint2 p; p.x = packbf2(w.x, w.y); p.y = packbf2(w.z, w.w);
            ((uint2*)Wb)[idx] = p;
        }
    } else {                              // madd: NB*SEQ = 4096 entries
        #pragma unroll
        for (int i = 0; i < 16; ++i) {
            int idx = tid + i * 256;
            maddG[idx] = mask[idx] ? 0.f : MADD2;
        }
    }
}

// ---------------------------------------------------------------------------
// Kernel 1: per-head QKV projection.  grid (SEQ/128, NH, 3*NB), block 256.
// Q,K out: [n][h][l][d] bf16 (Q pre-scaled by QSCALE).  V out: [n][h][d][l].
// ---------------------------------------------------------------------------
__global__ __launch_bounds__(256) void qkv_kernel(
    const float* __restrict__ Qin, const float* __restrict__ Kin,
    const float* __restrict__ Vin,
    const unsigned short* __restrict__ Wqb, const unsigned short* __restrict__ Wkb,
    const unsigned short* __restrict__ Wvb, const float* __restrict__ bq,
    unsigned short* __restrict__ Qp, unsigned short* __restrict__ Kp,
    unsigned short* __restrict__ Vtp)
{
    const int lt = blockIdx.x;          // 128-row l tile
    const int h  = blockIdx.y;
    const int tz = blockIdx.z;
    const int t  = tz >> 1, n = tz & 1;

    const float* X; const unsigned short* Wb;
    if (t == 0)      { X = Qin; Wb = Wqb; }
    else if (t == 1) { X = Kin; Wb = Wkb; }
    else             { X = Vin; Wb = Wvb; }

    __shared__ __align__(16) unsigned short sX[128][70];
    __shared__ __align__(16) unsigned short sT[64][136];

    const int tid = threadIdx.x, wave = tid >> 6, lane = tid & 63;
    const int ln = lane & 15, quad = lane >> 4;

    #pragma unroll
    for (int i = 0; i < 8; ++i) {
        int flat = tid + i * 256;
        int r = flat >> 4, c4 = flat & 15;
        float4 xv = *(const float4*)(X + ((size_t)(n * SEQ + lt * 128 + r)) * EMB + h * HD + c4 * 4);
        uint2 xp; xp.x = packbf2(xv.x, xv.y); xp.y = packbf2(xv.z, xv.w);
        *(uint2*)&sX[r][c4 * 4] = xp;
    }
    short8 wf0[4], wf1[4];
    #pragma unroll
    for (int nt = 0; nt < 4; ++nt) {
        wf0[nt] = *(const short8*)(Wb + (nt * 16 + ln) * HD + quad * 8);
        wf1[nt] = *(const short8*)(Wb + (nt * 16 + ln) * HD + 32 + quad * 8);
    }
    __syncthreads();

    f32x4 acc[2][4];
    #pragma unroll
    for (int set = 0; set < 2; ++set) {
        short8 af0 = *(const short8*)&sX[wave * 32 + set * 16 + ln][quad * 8];
        short8 af1 = *(const short8*)&sX[wave * 32 + set * 16 + ln][32 + quad * 8];
        #pragma unroll
        for (int nt = 0; nt < 4; ++nt) {
            f32x4 a = {0.f, 0.f, 0.f, 0.f};
            a = MFMA(af0, wf0[nt], a);
            a = MFMA(af1, wf1[nt], a);
            acc[set][nt] = a;
        }
    }

    if (t == 0) {   // bias then fold softmax scale (incl. log2e)
        #pragma unroll
        for (int nt = 0; nt < 4; ++nt) {
            float bb = bq[nt * 16 + ln];
            #pragma unroll
            for (int set = 0; set < 2; ++set)
                #pragma unroll
                for (int a = 0; a < 4; ++a)
                    acc[set][nt][a] = (acc[set][nt][a] + bb) * QSCALE;
        }
    }

    if (t < 2) {
        unsigned short* Out = (t == 0) ? Qp : Kp;
        #pragma unroll
        for (int set = 0; set < 2; ++set)
            #pragma unroll
            for (int a = 0; a < 4; ++a) {
                size_t row = (size_t)((n * NH + h) * SEQ + lt * 128 + wave * 32 + set * 16 + quad * 4 + a);
                #pragma unroll
                for (int nt = 0; nt < 4; ++nt)
                    Out[row * HD + nt * 16 + ln] = f2bf(acc[set][nt][a]);
            }
    } else {
        #pragma unroll
        for (int set = 0; set < 2; ++set)
            #pragma unroll
            for (int nt = 0; nt < 4; ++nt)
                #pragma unroll
                for (int a = 0; a < 4; ++a)
                    sT[nt * 16 + ln][wave * 32 + set * 16 + quad * 4 + a] = f2bf(acc[set][nt][a]);
        __syncthreads();
        #pragma unroll
        for (int i = 0; i < 4; ++i) {
            int flat = tid + i * 256;
            int r = flat >> 4, c8 = flat & 15;
            *(float4*)(Vtp + ((size_t)((n * NH + h) * HD + r)) * SEQ + lt * 128 + c8 * 8) =
                *(const float4*)&sT[r][c8 * 8];
        }
    }
}

// ---------------------------------------------------------------------------
// Kernel 2: flash attention v9 — pipelined LDS-staged K/V (T3 2-phase).
// Diagnosis r0-r3: wall = serialized per-wave L2 round trips (17 dependent
// loads/iter, no cross-iter prefetch because the asm memory clobber is a
// compiler barrier); occupancy changes (r3: 44%) made it WORSE (2x private
// K/V traffic).  VALU/MFMA issue-time identical across rounds -> pure stall.
// v9 structure:
//   - q-tile 128/block, 4 waves x 32 q-rows, NO key-split (no combine).
//   - K,V 64x64 tiles double-buffered in LDS, staged one tile ahead via
//     global_load_lds(16B); one __syncthreads per iter (its implicit
//     vmcnt(0) drain has a full iteration of cover) -> latency hidden.
//   - gload_lds writes linearly, so the tile is stored with chunk-XOR
//     content permutation done on the GLOBAL source address (lane-constant
//     (l&7)^(l>>3)); ds_read_b128 fragment reads apply the same XOR
//     (involution) -> conflict-free (was 16-way).  sP gets the same XOR.
//   - K/V L2 traffic halves vs r0 (256 MB total) and is shared by 4 waves.
// grid (NB*NH, SEQ/128), block 256 (4 waves).  Plain launch_bounds (no
// min-waves floor: v6 lesson).
// ---------------------------------------------------------------------------
__global__ __launch_bounds__(256) void flash_kernel(
    const unsigned short* __restrict__ Qp, const unsigned short* __restrict__ Kp,
    const unsigned short* __restrict__ Vtp, const float* __restrict__ maddG,
    unsigned short* __restrict__ A /* [n][l][EMB] bf16 */)
{
    const int nh = blockIdx.x;
    const int qt = blockIdx.y;            // 128-row q tile
    const int n  = nh >> 4, h = nh & 15;

    const int tid  = threadIdx.x;
    const int wave = tid >> 6, lane = tid & 63;
    const int ln   = lane & 15, quad = lane >> 4;
    const int ln7  = lane & 7;

    __shared__ __align__(16) unsigned short Kb[2][64 * 64];   // 16 KiB
    __shared__ __align__(16) unsigned short Vb[2][64 * 64];   // 16 KiB
    __shared__ __align__(16) unsigned short sP[4][32 * 64];   // 16 KiB
    unsigned short* sPw = sP[wave];

    // Q B-fragments: wave owns q rows qt*128 + wave*32 + set*16 + ln
    const unsigned short* Qb = Qp + ((size_t)nh * SEQ + qt * 128 + wave * 32) * HD;
    short8 qf[2][2];
    #pragma unroll
    for (int set = 0; set < 2; ++set) {
        qf[set][0] = *(const short8*)(Qb + (set * 16 + ln) * HD + quad * 8);
        qf[set][1] = *(const short8*)(Qb + (set * 16 + ln) * HD + 32 + quad * 8);
    }

    const unsigned short* Kg = Kp  + (size_t)nh * SEQ * HD;
    const unsigned short* Vg = Vtp + (size_t)nh * HD * SEQ;
    const float* mb = maddG + n * SEQ;

    // staging geometry: each gload16 = 1 KiB = 8 rows of 128B.  Wave w stages
    // rows [16w, 16w+16) of both K and V (2 instrs each).  Source chunk is
    // pre-swizzled: lane l fetches chunk (l&7)^(l>>3) of row (l>>3) so that
    // LDS(row, c) holds global(row, c ^ (row&7)).
    const int r8  = lane >> 3;                       // 0..7
    const int swz = ((lane & 7) ^ r8) << 3;          // shorts within row

    f32x4 o[2][4];
    #pragma unroll
    for (int s2 = 0; s2 < 2; ++s2)
        #pragma unroll
        for (int dt = 0; dt < 4; ++dt) o[s2][dt] = (f32x4){0.f, 0.f, 0.f, 0.f};
    float lsum[2] = {0.f, 0.f};

    #define STAGE(buf, kt_) do {                                                  \
        const unsigned short* kg_ = Kg + ((size_t)((kt_) * 64 + wave * 16 + r8)) * HD + swz; \
        const unsigned short* vg_ = Vg + ((size_t)(wave * 16 + r8)) * SEQ + (kt_) * 64 + swz; \
        unsigned short* kl_ = &Kb[buf][wave * 16 * 64];                           \
        unsigned short* vl_ = &Vb[buf][wave * 16 * 64];                           \
        gload16(kg_,            kl_);                                             \
        gload16(kg_ + 8 * HD,   kl_ + 8 * 64);                                    \
        gload16(vg_,            vl_);                                             \
        gload16(vg_ + 8 * SEQ,  vl_ + 8 * 64);                                    \
    } while (0)

    STAGE(0, 0);
    __syncthreads();                       // drains vmcnt -> tile 0 ready
    int cur = 0;

    for (int kt = 0; kt < SEQ / 64; ++kt) {
        // mask adds for this tile (tiny, L1/L2-hot; issued before staging for distance)
        float4 md[4];
        #pragma unroll
        for (int nt = 0; nt < 4; ++nt)
            md[nt] = *(const float4*)(mb + kt * 64 + nt * 16 + quad * 4);

        if (kt + 1 < SEQ / 64) STAGE(cur ^ 1, kt + 1);   // async prefetch

        // ---- S^T = K Q^T, softmax numerator, P -> sP (swizzled) ----
        const unsigned short* Kc = Kb[cur];
        #pragma unroll
        for (int nt = 0; nt < 4; ++nt) {
            short8 kf0 = *(const short8*)&Kc[(nt * 16 + ln) * 64 + (((quad)     ^ ln7) << 3)];
            short8 kf1 = *(const short8*)&Kc[(nt * 16 + ln) * 64 + (((quad + 4) ^ ln7) << 3)];
            #pragma unroll
            for (int set = 0; set < 2; ++set) {
                f32x4 z = {0.f, 0.f, 0.f, 0.f};
                z = MFMA(kf0, qf[set][0], z);
                z = MFMA(kf1, qf[set][1], z);
                // S^T C-layout: (key = nt*16+quad*4+a, q = set*16+ln)
                float p0 = EXP2(fminf(z[0] + md[nt].x, 80.f));
                float p1 = EXP2(fminf(z[1] + md[nt].y, 80.f));
                float p2 = EXP2(fminf(z[2] + md[nt].z, 80.f));
                float p3 = EXP2(fminf(z[3] + md[nt].w, 80.f));
                lsum[set] += (p0 + p1) + (p2 + p3);
                uint2 w; w.x = packbf2(p0, p1); w.y = packbf2(p2, p3);
                int prow  = set * 16 + ln;
                int chunk = nt * 2 + (quad >> 1);
                *(uint2*)&sPw[prow * 64 + ((chunk ^ ln7) << 3) + (quad & 1) * 4] = w;
            }
        }
        asm volatile("s_waitcnt lgkmcnt(0)" ::: "memory");   // per-wave P slice

        // ---- O += P V ----
        const unsigned short* Vc = Vb[cur];
        short8 pf[2][2];
        #pragma unroll
        for (int set = 0; set < 2; ++set) {
            pf[set][0] = *(const short8*)&sPw[(set * 16 + ln) * 64 + (((quad)     ^ ln7) << 3)];
            pf[set][1] = *(const short8*)&sPw[(set * 16 + ln) * 64 + (((quad + 4) ^ ln7) << 3)];
        }
        #pragma unroll
        for (int dt = 0; dt < 4; ++dt) {
            short8 vf0 = *(const short8*)&Vc[(dt * 16 + ln) * 64 + (((quad)     ^ ln7) << 3)];
            short8 vf1 = *(const short8*)&Vc[(dt * 16 + ln) * 64 + (((quad + 4) ^ ln7) << 3)];
            #pragma unroll
            for (int set = 0; set < 2; ++set) {
                o[set][dt] = MFMA(pf[set][0], vf0, o[set][dt]);
                o[set][dt] = MFMA(pf[set][1], vf1, o[set][dt]);
            }
        }

        __syncthreads();   // implicit vmcnt(0)+lgkmcnt(0): prefetch landed, all reads done
        cur ^= 1;
    }
    #undef STAGE

    // ---- normalize own rows and write (no cross-wave combine) ----
    #pragma unroll
    for (int set = 0; set < 2; ++set) {
        float l = lsum[set];
        l += __shfl_xor(l, 16);
        l += __shfl_xor(l, 32);            // full sum for q = set*16+ln, all lanes
        #pragma unroll
        for (int a = 0; a < 4; ++a) {
            float inv = 1.0f / __shfl(l, quad * 4 + a);
            size_t row = (size_t)(n * SEQ + qt * 128 + wave * 32 + set * 16 + quad * 4 + a);
            #pragma unroll
            for (int dt = 0; dt < 4; ++dt)
                A[row * EMB + h * HD + dt * 16 + ln] = f2bf(o[set][dt][a] * inv);
        }
    }
}

// ---------------------------------------------------------------------------
// Kernel 3: out = A @ Wo^T + bo, 128x128 tile (m93 structure).
// grid (EMB/128, NB*SEQ/128), block 256 (2x2 waves of 64x64).
// ---------------------------------------------------------------------------
__global__ __launch_bounds__(256) void outproj_kernel(
    const unsigned short* __restrict__ A, const unsigned short* __restrict__ Wob,
    const float* __restrict__ bo, float* __restrict__ Out)
{
    const int ct = blockIdx.x;   // 128-col tile
    const int rt = blockIdx.y;   // 128-row tile

    const int tid  = threadIdx.x;
    const int wave = tid >> 6, lane = tid & 63;
    const int ln   = lane & 15, quad = lane >> 4;
    const int wm   = wave >> 1, wn = wave & 1;

    __shared__ __align__(16) unsigned short sA[128][72];
    __shared__ __align__(16) unsigned short sB[128][72];

    f32x4 acc[4][4];
    #pragma unroll
    for (int i = 0; i < 4; ++i)
        #pragma unroll
        for (int j = 0; j < 4; ++j) acc[i][j] = (f32x4){0.f, 0.f, 0.f, 0.f};

    for (int kc = 0; kc < EMB / 64; ++kc) {
        __syncthreads();
        #pragma unroll
        for (int i = 0; i < 4; ++i) {
            int flat = tid + i * 256;          // 0..1023, 8-bf16 groups
            int r = flat >> 3, c8 = flat & 7;
            *(float4*)&sA[r][c8 * 8] =
                *(const float4*)(A + (size_t)(rt * 128 + r) * EMB + kc * 64 + c8 * 8);
            *(float4*)&sB[r][c8 * 8] =
                *(const float4*)(Wob + (size_t)(ct * 128 + r) * EMB + kc * 64 + c8 * 8);
        }
        __syncthreads();

        #pragma unroll
        for (int ks = 0; ks < 2; ++ks) {
            short8 af[4], bf[4];
            #pragma unroll
            for (int i = 0; i < 4; ++i)
                af[i] = *(const short8*)&sA[wm * 64 + i * 16 + ln][ks * 32 + quad * 8];
            #pragma unroll
            for (int j = 0; j < 4; ++j)
                bf[j] = *(const short8*)&sB[wn * 64 + j * 16 + ln][ks * 32 + quad * 8];
            #pragma unroll
            for (int i = 0; i < 4; ++i)
                #pragma unroll
                for (int j = 0; j < 4; ++j)
                    acc[i][j] = MFMA(af[i], bf[j], acc[i][j]);
        }
    }

    #pragma unroll
    for (int j = 0; j < 4; ++j) {
        int col = ct * 128 + wn * 64 + j * 16 + ln;
        float bb = bo[col];
        #pragma unroll
        for (int i = 0; i < 4; ++i)
            #pragma unroll
            for (int a = 0; a < 4; ++a) {
                size_t row = (size_t)(rt * 128 + wm * 64 + i * 16 + quad * 4 + a);
                Out[row * EMB + col] = acc[i][j][a] + bb;
            }
    }
}

// ---------------------------------------------------------------------------
extern "C" void kernel_launch(void* const* d_in, const int* in_sizes, int n_in,
                              void* d_out, int out_size, void* d_ws, size_t ws_size,
                              hipStream_t stream) {
    const float* values = (const float*)d_in[0];
    const float* key_   = (const float*)d_in[1];
    const float* query  = (const float*)d_in[2];
    const int*   mask   = (const int*)d_in[3];
    const float* Wv     = (const float*)d_in[4];
    const float* Wk     = (const float*)d_in[5];
    const float* Wq     = (const float*)d_in[6];
    const float* bq     = (const float*)d_in[7];
    const float* Wo     = (const float*)d_in[8];
    const float* bo     = (const float*)d_in[9];
    float* out = (float*)d_out;

    const size_t NHLD = (size_t)NB * NH * SEQ * HD;   // 4,194,304

    unsigned short* ws = (unsigned short*)d_ws;
    unsigned short* Qp    = ws;
    unsigned short* Kp    = ws + NHLD;
    unsigned short* Vtp   = ws + 2 * NHLD;
    unsigned short* Aattn = ws + 3 * NHLD;
    unsigned short* Wob   = ws + 4 * NHLD;                  // EMB*EMB
    unsigned short* Wqb   = Wob + (size_t)EMB * EMB;
    unsigned short* Wkb   = Wqb + HD * HD;
    unsigned short* Wvb   = Wkb + HD * HD;
    float* maddG = (float*)(Wvb + HD * HD);                 // NB*SEQ floats

    cvt_kernel<<<dim3(1028), 256, 0, stream>>>(
        Wo, Wq, Wk, Wv, mask, Wob, Wqb, Wkb, Wvb, maddG);
    qkv_kernel<<<dim3(SEQ / 128, NH, 3 * NB), 256, 0, stream>>>(
        query, key_, values, Wqb, Wkb, Wvb, bq, Qp, Kp, Vtp);
    flash_kernel<<<dim3(NB * NH, SEQ / 128), 256, 0, stream>>>(
        Qp, Kp, Vtp, maddG, Aattn);
    outproj_kernel<<<dim3(EMB / 128, NB * SEQ / 128), 256, 0, stream>>>(
        Aattn, Wob, bo, out);
}

// Round 6
// 201.815 us; speedup vs baseline: 1.3054x; 1.0162x over previous
//
#include <hip/hip_runtime.h>
#include <hip/hip_bf16.h>
#include <string.h>

#define NB   2
#define SEQ  2048
#define EMB  1024
#define NH   16
#define HD   64
// softmax uses exp2: fold SCALE*log2(e) into Q pre-scale and the mask table
#define QSCALE 0.045084219f       // (1/32) * log2(e)
#define MADD2  -4.5084219e18f     // -1e20 * (1/32) * log2(e)

typedef __attribute__((ext_vector_type(8))) short short8;   // 8 x bf16
typedef __attribute__((ext_vector_type(4))) float f32x4;    // MFMA C/D

#define MFMA(a, b, c) __builtin_amdgcn_mfma_f32_16x16x32_bf16(a, b, c, 0, 0, 0)
#define EXP2(x) __builtin_amdgcn_exp2f(x)

__device__ __forceinline__ unsigned short f2bf(float x) {
    union { float f; unsigned u; } v; v.f = x;
    unsigned r = v.u + 0x7fffu + ((v.u >> 16) & 1u);   // RNE
    return (unsigned short)(r >> 16);
}
__device__ __forceinline__ unsigned packbf2(float a, float b) {
    __hip_bfloat162 h = __float22bfloat162_rn(make_float2(a, b));  // hw v_cvt_pk
    unsigned u; memcpy(&u, &h, 4);
    return u;
}
// async global->LDS, 16B per lane; LDS dest = uniform base + lane*16 (linear)
__device__ __forceinline__ void gload16(const void* g, void* l) {
    __builtin_amdgcn_global_load_lds(
        (const __attribute__((address_space(1))) void*)g,
        (__attribute__((address_space(3))) void*)l, 16, 0, 0);
}

// ---------------------------------------------------------------------------
// Kernel 0: convert Wo/Wq/Wk/Wv fp32->bf16, build exp2-domain madd table.
// ---------------------------------------------------------------------------
__global__ __launch_bounds__(256) void cvt_kernel(
    const float* __restrict__ Wo, const float* __restrict__ Wq,
    const float* __restrict__ Wk, const float* __restrict__ Wv,
    const int* __restrict__ mask,
    unsigned short* __restrict__ Wob, unsigned short* __restrict__ Wqb,
    unsigned short* __restrict__ Wkb, unsigned short* __restrict__ Wvb,
    float* __restrict__ maddG)
{
    const int b = blockIdx.x, tid = threadIdx.x;
    if (b < 1024) {                       // Wo: 262144 float4
        int idx = b * 256 + tid;
        float4 w = ((const float4*)Wo)[idx];
        uint2 p; p.x = packbf2(w.x, w.y); p.y = packbf2(w.z, w.w);
        ((uint2*)Wob)[idx] = p;
    } else if (b < 1027) {                // Wq/Wk/Wv: 1024 float4 each
        const float* W = (b == 1024) ? Wq : (b == 1025) ? Wk : Wv;
        unsigned short* Wb = (b == 1024) ? Wqb : (b == 1025) ? Wkb : Wvb;
        #pragma unroll
        for (int i = 0; i < 4; ++i) {
            int idx = tid + i * 256;
            float4 w = ((const float4*)W)[idx];
            uint2 p; p.x = packbf2(w.x, w.y); p.y = packbf2(w.z, w.w);
            ((uint2*)Wb)[idx] = p;
        }
    } else {                              // madd: NB*SEQ = 4096 entries
        #pragma unroll
        for (int i = 0; i < 16; ++i) {
            int idx = tid + i * 256;
            maddG[idx] = mask[idx] ? 0.f : MADD2;
        }
    }
}

// ---------------------------------------------------------------------------
// Kernel 1: per-head QKV projection.  grid (SEQ/128, NH, 3*NB), block 256.
// Q,K out: [n][h][l][d] bf16 (Q pre-scaled by QSCALE).  V out: [n][h][d][l].
// ---------------------------------------------------------------------------
__global__ __launch_bounds__(256) void qkv_kernel(
    const float* __restrict__ Qin, const float* __restrict__ Kin,
    const float* __restrict__ Vin,
    const unsigned short* __restrict__ Wqb, const unsigned short* __restrict__ Wkb,
    const unsigned short* __restrict__ Wvb, const float* __restrict__ bq,
    unsigned short* __restrict__ Qp, unsigned short* __restrict__ Kp,
    unsigned short* __restrict__ Vtp)
{
    const int lt = blockIdx.x;          // 128-row l tile
    const int h  = blockIdx.y;
    const int tz = blockIdx.z;
    const int t  = tz >> 1, n = tz & 1;

    const float* X; const unsigned short* Wb;
    if (t == 0)      { X = Qin; Wb = Wqb; }
    else if (t == 1) { X = Kin; Wb = Wkb; }
    else             { X = Vin; Wb = Wvb; }

    __shared__ __align__(16) unsigned short sX[128][70];
    __shared__ __align__(16) unsigned short sT[64][136];

    const int tid = threadIdx.x, wave = tid >> 6, lane = tid & 63;
    const int ln = lane & 15, quad = lane >> 4;

    #pragma unroll
    for (int i = 0; i < 8; ++i) {
        int flat = tid + i * 256;
        int r = flat >> 4, c4 = flat & 15;
        float4 xv = *(const float4*)(X + ((size_t)(n * SEQ + lt * 128 + r)) * EMB + h * HD + c4 * 4);
        uint2 xp; xp.x = packbf2(xv.x, xv.y); xp.y = packbf2(xv.z, xv.w);
        *(uint2*)&sX[r][c4 * 4] = xp;
    }
    short8 wf0[4], wf1[4];
    #pragma unroll
    for (int nt = 0; nt < 4; ++nt) {
        wf0[nt] = *(const short8*)(Wb + (nt * 16 + ln) * HD + quad * 8);
        wf1[nt] = *(const short8*)(Wb + (nt * 16 + ln) * HD + 32 + quad * 8);
    }
    __syncthreads();

    f32x4 acc[2][4];
    #pragma unroll
    for (int set = 0; set < 2; ++set) {
        short8 af0 = *(const short8*)&sX[wave * 32 + set * 16 + ln][quad * 8];
        short8 af1 = *(const short8*)&sX[wave * 32 + set * 16 + ln][32 + quad * 8];
        #pragma unroll
        for (int nt = 0; nt < 4; ++nt) {
            f32x4 a = {0.f, 0.f, 0.f, 0.f};
            a = MFMA(af0, wf0[nt], a);
            a = MFMA(af1, wf1[nt], a);
            acc[set][nt] = a;
        }
    }

    if (t == 0) {   // bias then fold softmax scale (incl. log2e)
        #pragma unroll
        for (int nt = 0; nt < 4; ++nt) {
            float bb = bq[nt * 16 + ln];
            #pragma unroll
            for (int set = 0; set < 2; ++set)
                #pragma unroll
                for (int a = 0; a < 4; ++a)
                    acc[set][nt][a] = (acc[set][nt][a] + bb) * QSCALE;
        }
    }

    if (t < 2) {
        unsigned short* Out = (t == 0) ? Qp : Kp;
        #pragma unroll
        for (int set = 0; set < 2; ++set)
            #pragma unroll
            for (int a = 0; a < 4; ++a) {
                size_t row = (size_t)((n * NH + h) * SEQ + lt * 128 + wave * 32 + set * 16 + quad * 4 + a);
                #pragma unroll
                for (int nt = 0; nt < 4; ++nt)
                    Out[row * HD + nt * 16 + ln] = f2bf(acc[set][nt][a]);
            }
    } else {
        #pragma unroll
        for (int set = 0; set < 2; ++set)
            #pragma unroll
            for (int nt = 0; nt < 4; ++nt)
                #pragma unroll
                for (int a = 0; a < 4; ++a)
                    sT[nt * 16 + ln][wave * 32 + set * 16 + quad * 4 + a] = f2bf(acc[set][nt][a]);
        __syncthreads();
        #pragma unroll
        for (int i = 0; i < 4; ++i) {
            int flat = tid + i * 256;
            int r = flat >> 4, c8 = flat & 15;
            *(float4*)(Vtp + ((size_t)((n * NH + h) * HD + r)) * SEQ + lt * 128 + c8 * 8) =
                *(const float4*)&sT[r][c8 * 8];
        }
    }
}

// ---------------------------------------------------------------------------
// Kernel 2: flash attention v10 — same pipeline as v9, 2x the waves.
// (Resubmission: round-5 bench was an infra failure — container died before
// running; no counters.  Source is unchanged from the round-4 proposal.)
// v9 post-mortem: pipeline works (77us, VALUBusy 24->51%, conflicts -40%),
// but occupancy is grid-limited: each wave owns 32 q-rows -> 2048 waves total
// = 8/CU = 2/SIMD, so the VALU chain (exp2+pack+swizzle-addr) has only one
// partner wave to overlap with.
// v10: per-wave q-tile 32->16 rows -> 4096 waves.  Block = 4 waves x 16 q
// (64-row q-tile), grid.y = SEQ/64 -> 1024 blocks = 4 blocks/CU x 4 waves =
// 16 waves/CU (4/SIMD).  LDS 40KB/block (K/V dbuf 32K + sP 8K); 4x40=160KB
// exactly fits.  Per-wave state halves (o[4], one q set) -> no spill.
// K/V staging traffic doubles (512MB total, ~2MB/XCD working set, L2-hot,
// heads stay XCD-pinned: same-head blocks are 32 apart in linear id).
// Swizzle scheme unchanged: LDS(row,c) = global(row, c^(row&7)) via
// pre-swizzled global source (rule 21), same XOR on all ds_reads; sP same.
// grid (NB*NH, SEQ/64), block 256 (4 waves).
// ---------------------------------------------------------------------------
__global__ __launch_bounds__(256) void flash_kernel(
    const unsigned short* __restrict__ Qp, const unsigned short* __restrict__ Kp,
    const unsigned short* __restrict__ Vtp, const float* __restrict__ maddG,
    unsigned short* __restrict__ A /* [n][l][EMB] bf16 */)
{
    const int nh = blockIdx.x;
    const int qt = blockIdx.y;            // 64-row q tile
    const int n  = nh >> 4, h = nh & 15;

    const int tid  = threadIdx.x;
    const int wave = tid >> 6, lane = tid & 63;
    const int ln   = lane & 15, quad = lane >> 4;
    const int ln7  = lane & 7;

    __shared__ __align__(16) unsigned short Kb[2][64 * 64];   // 16 KiB
    __shared__ __align__(16) unsigned short Vb[2][64 * 64];   // 16 KiB
    __shared__ __align__(16) unsigned short sP[4][16 * 64];   // 8 KiB
    unsigned short* sPw = sP[wave];

    // Q B-fragments: wave owns q rows qt*64 + wave*16 + ln
    const unsigned short* Qb = Qp + ((size_t)nh * SEQ + qt * 64 + wave * 16) * HD;
    short8 qf0 = *(const short8*)(Qb + ln * HD + quad * 8);
    short8 qf1 = *(const short8*)(Qb + ln * HD + 32 + quad * 8);

    const unsigned short* Kg = Kp  + (size_t)nh * SEQ * HD;
    const unsigned short* Vg = Vtp + (size_t)nh * HD * SEQ;
    const float* mb = maddG + n * SEQ;

    // staging geometry: each gload16 = 1 KiB = 8 rows of 128B.  Wave w stages
    // rows [16w, 16w+16) of both K and V (2 instrs each).  Source chunk is
    // pre-swizzled: lane l fetches chunk (l&7)^(l>>3) of row (l>>3) so that
    // LDS(row, c) holds global(row, c ^ (row&7)).
    const int r8  = lane >> 3;                       // 0..7
    const int swz = ((lane & 7) ^ r8) << 3;          // shorts within row

    f32x4 o[4];
    #pragma unroll
    for (int dt = 0; dt < 4; ++dt) o[dt] = (f32x4){0.f, 0.f, 0.f, 0.f};
    float lsum = 0.f;

    #define STAGE(buf, kt_) do {                                                  \
        const unsigned short* kg_ = Kg + ((size_t)((kt_) * 64 + wave * 16 + r8)) * HD + swz; \
        const unsigned short* vg_ = Vg + ((size_t)(wave * 16 + r8)) * SEQ + (kt_) * 64 + swz; \
        unsigned short* kl_ = &Kb[buf][wave * 16 * 64];                           \
        unsigned short* vl_ = &Vb[buf][wave * 16 * 64];                           \
        gload16(kg_,            kl_);                                             \
        gload16(kg_ + 8 * HD,   kl_ + 8 * 64);                                    \
        gload16(vg_,            vl_);                                             \
        gload16(vg_ + 8 * SEQ,  vl_ + 8 * 64);                                    \
    } while (0)

    STAGE(0, 0);
    __syncthreads();                       // drains vmcnt -> tile 0 ready
    int cur = 0;

    for (int kt = 0; kt < SEQ / 64; ++kt) {
        // mask adds for this tile (tiny, L1/L2-hot)
        float4 md[4];
        #pragma unroll
        for (int nt = 0; nt < 4; ++nt)
            md[nt] = *(const float4*)(mb + kt * 64 + nt * 16 + quad * 4);

        if (kt + 1 < SEQ / 64) STAGE(cur ^ 1, kt + 1);   // async prefetch

        // ---- S^T = K Q^T, softmax numerator, P -> sP (swizzled) ----
        const unsigned short* Kc = Kb[cur];
        #pragma unroll
        for (int nt = 0; nt < 4; ++nt) {
            short8 kf0 = *(const short8*)&Kc[(nt * 16 + ln) * 64 + (((quad)     ^ ln7) << 3)];
            short8 kf1 = *(const short8*)&Kc[(nt * 16 + ln) * 64 + (((quad + 4) ^ ln7) << 3)];
            f32x4 z = {0.f, 0.f, 0.f, 0.f};
            z = MFMA(kf0, qf0, z);
            z = MFMA(kf1, qf1, z);
            // S^T C-layout: (key = nt*16+quad*4+a, q = ln)
            float p0 = EXP2(fminf(z[0] + md[nt].x, 80.f));
            float p1 = EXP2(fminf(z[1] + md[nt].y, 80.f));
            float p2 = EXP2(fminf(z[2] + md[nt].z, 80.f));
            float p3 = EXP2(fminf(z[3] + md[nt].w, 80.f));
            lsum += (p0 + p1) + (p2 + p3);
            uint2 w; w.x = packbf2(p0, p1); w.y = packbf2(p2, p3);
            int chunk = nt * 2 + (quad >> 1);
            *(uint2*)&sPw[ln * 64 + ((chunk ^ ln7) << 3) + (quad & 1) * 4] = w;
        }
        asm volatile("s_waitcnt lgkmcnt(0)" ::: "memory");   // per-wave P slice

        // ---- O += P V ----
        const unsigned short* Vc = Vb[cur];
        short8 pf0 = *(const short8*)&sPw[ln * 64 + (((quad)     ^ ln7) << 3)];
        short8 pf1 = *(const short8*)&sPw[ln * 64 + (((quad + 4) ^ ln7) << 3)];
        #pragma unroll
        for (int dt = 0; dt < 4; ++dt) {
            short8 vf0 = *(const short8*)&Vc[(dt * 16 + ln) * 64 + (((quad)     ^ ln7) << 3)];
            short8 vf1 = *(const short8*)&Vc[(dt * 16 + ln) * 64 + (((quad + 4) ^ ln7) << 3)];
            o[dt] = MFMA(pf0, vf0, o[dt]);
            o[dt] = MFMA(pf1, vf1, o[dt]);
        }

        __syncthreads();   // implicit vmcnt(0)+lgkmcnt(0): prefetch landed, all reads done
        cur ^= 1;
    }
    #undef STAGE

    // ---- normalize own rows and write (no cross-wave combine) ----
    float l = lsum;
    l += __shfl_xor(l, 16);
    l += __shfl_xor(l, 32);               // full sum for q = ln, all lanes
    #pragma unroll
    for (int a = 0; a < 4; ++a) {
        float inv = 1.0f / __shfl(l, quad * 4 + a);
        size_t row = (size_t)(n * SEQ + qt * 64 + wave * 16 + quad * 4 + a);
        #pragma unroll
        for (int dt = 0; dt < 4; ++dt)
            A[row * EMB + h * HD + dt * 16 + ln] = f2bf(o[dt][a] * inv);
    }
}

// ---------------------------------------------------------------------------
// Kernel 3: out = A @ Wo^T + bo, 128x128 tile (m93 structure).
// grid (EMB/128, NB*SEQ/128), block 256 (2x2 waves of 64x64).
// ---------------------------------------------------------------------------
__global__ __launch_bounds__(256) void outproj_kernel(
    const unsigned short* __restrict__ A, const unsigned short* __restrict__ Wob,
    const float* __restrict__ bo, float* __restrict__ Out)
{
    const int ct = blockIdx.x;   // 128-col tile
    const int rt = blockIdx.y;   // 128-row tile

    const int tid  = threadIdx.x;
    const int wave = tid >> 6, lane = tid & 63;
    const int ln   = lane & 15, quad = lane >> 4;
    const int wm   = wave >> 1, wn = wave & 1;

    __shared__ __align__(16) unsigned short sA[128][72];
    __shared__ __align__(16) unsigned short sB[128][72];

    f32x4 acc[4][4];
    #pragma unroll
    for (int i = 0; i < 4; ++i)
        #pragma unroll
        for (int j = 0; j < 4; ++j) acc[i][j] = (f32x4){0.f, 0.f, 0.f, 0.f};

    for (int kc = 0; kc < EMB / 64; ++kc) {
        __syncthreads();
        #pragma unroll
        for (int i = 0; i < 4; ++i) {
            int flat = tid + i * 256;          // 0..1023, 8-bf16 groups
            int r = flat >> 3, c8 = flat & 7;
            *(float4*)&sA[r][c8 * 8] =
                *(const float4*)(A + (size_t)(rt * 128 + r) * EMB + kc * 64 + c8 * 8);
            *(float4*)&sB[r][c8 * 8] =
                *(const float4*)(Wob + (size_t)(ct * 128 + r) * EMB + kc * 64 + c8 * 8);
        }
        __syncthreads();

        #pragma unroll
        for (int ks = 0; ks < 2; ++ks) {
            short8 af[4], bf[4];
            #pragma unroll
            for (int i = 0; i < 4; ++i)
                af[i] = *(const short8*)&sA[wm * 64 + i * 16 + ln][ks * 32 + quad * 8];
            #pragma unroll
            for (int j = 0; j < 4; ++j)
                bf[j] = *(const short8*)&sB[wn * 64 + j * 16 + ln][ks * 32 + quad * 8];
            #pragma unroll
            for (int i = 0; i < 4; ++i)
                #pragma unroll
                for (int j = 0; j < 4; ++j)
                    acc[i][j] = MFMA(af[i], bf[j], acc[i][j]);
        }
    }

    #pragma unroll
    for (int j = 0; j < 4; ++j) {
        int col = ct * 128 + wn * 64 + j * 16 + ln;
        float bb = bo[col];
        #pragma unroll
        for (int i = 0; i < 4; ++i)
            #pragma unroll
            for (int a = 0; a < 4; ++a) {
                size_t row = (size_t)(rt * 128 + wm * 64 + i * 16 + quad * 4 + a);
                Out[row * EMB + col] = acc[i][j][a] + bb;
            }
    }
}

// ---------------------------------------------------------------------------
extern "C" void kernel_launch(void* const* d_in, const int* in_sizes, int n_in,
                              void* d_out, int out_size, void* d_ws, size_t ws_size,
                              hipStream_t stream) {
    const float* values = (const float*)d_in[0];
    const float* key_   = (const float*)d_in[1];
    const float* query  = (const float*)d_in[2];
    const int*   mask   = (const int*)d_in[3];
    const float* Wv     = (const float*)d_in[4];
    const float* Wk     = (const float*)d_in[5];
    const float* Wq     = (const float*)d_in[6];
    const float* bq     = (const float*)d_in[7];
    const float* Wo     = (const float*)d_in[8];
    const float* bo     = (const float*)d_in[9];
    float* out = (float*)d_out;

    const size_t NHLD = (size_t)NB * NH * SEQ * HD;   // 4,194,304

    unsigned short* ws = (unsigned short*)d_ws;
    unsigned short* Qp    = ws;
    unsigned short* Kp    = ws + NHLD;
    unsigned short* Vtp   = ws + 2 * NHLD;
    unsigned short* Aattn = ws + 3 * NHLD;
    unsigned short* Wob   = ws + 4 * NHLD;                  // EMB*EMB
    unsigned short* Wqb   = Wob + (size_t)EMB * EMB;
    unsigned short* Wkb   = Wqb + HD * HD;
    unsigned short* Wvb   = Wkb + HD * HD;
    float* maddG = (float*)(Wvb + HD * HD);                 // NB*SEQ floats

    cvt_kernel<<<dim3(1028), 256, 0, stream>>>(
        Wo, Wq, Wk, Wv, mask, Wob, Wqb, Wkb, Wvb, maddG);
    qkv_kernel<<<dim3(SEQ / 128, NH, 3 * NB), 256, 0, stream>>>(
        query, key_, values, Wqb, Wkb, Wvb, bq, Qp, Kp, Vtp);
    flash_kernel<<<dim3(NB * NH, SEQ / 64), 256, 0, stream>>>(
        Qp, Kp, Vtp, maddG, Aattn);
    outproj_kernel<<<dim3(EMB / 128, NB * SEQ / 128), 256, 0, stream>>>(
        Aattn, Wob, bo, out);
}

// Round 7
// 192.895 us; speedup vs baseline: 1.3657x; 1.0462x over previous
//
#include <hip/hip_runtime.h>
#include <hip/hip_bf16.h>
#include <string.h>

#define NB   2
#define SEQ  2048
#define EMB  1024
#define NH   16
#define HD   64
// softmax uses exp2: fold SCALE*log2(e) into Q pre-scale
#define QSCALE 0.045084219f       // (1/32) * log2(e)

typedef __attribute__((ext_vector_type(8))) short short8;   // 8 x bf16
typedef __attribute__((ext_vector_type(4))) float f32x4;    // MFMA C/D

#define MFMA(a, b, c) __builtin_amdgcn_mfma_f32_16x16x32_bf16(a, b, c, 0, 0, 0)
#define EXP2(x) __builtin_amdgcn_exp2f(x)

__device__ __forceinline__ unsigned short f2bf(float x) {
    union { float f; unsigned u; } v; v.f = x;
    unsigned r = v.u + 0x7fffu + ((v.u >> 16) & 1u);   // RNE
    return (unsigned short)(r >> 16);
}
__device__ __forceinline__ unsigned packbf2(float a, float b) {
    __hip_bfloat162 h = __float22bfloat162_rn(make_float2(a, b));  // hw v_cvt_pk
    unsigned u; memcpy(&u, &h, 4);
    return u;
}
// async global->LDS, 16B per lane; LDS dest = uniform base + lane*16 (linear)
__device__ __forceinline__ void gload16(const void* g, void* l) {
    __builtin_amdgcn_global_load_lds(
        (const __attribute__((address_space(1))) void*)g,
        (__attribute__((address_space(3))) void*)l, 16, 0, 0);
}

// ---------------------------------------------------------------------------
// Kernel 0: convert Wo/Wq/Wk/Wv fp32->bf16, build bf16 mask vector (1.0/0.0).
// ---------------------------------------------------------------------------
__global__ __launch_bounds__(256) void cvt_kernel(
    const float* __restrict__ Wo, const float* __restrict__ Wq,
    const float* __restrict__ Wk, const float* __restrict__ Wv,
    const int* __restrict__ mask,
    unsigned short* __restrict__ Wob, unsigned short* __restrict__ Wqb,
    unsigned short* __restrict__ Wkb, unsigned short* __restrict__ Wvb,
    unsigned short* __restrict__ Mb)
{
    const int b = blockIdx.x, tid = threadIdx.x;
    if (b < 1024) {                       // Wo: 262144 float4
        int idx = b * 256 + tid;
        float4 w = ((const float4*)Wo)[idx];
        uint2 p; p.x = packbf2(w.x, w.y); p.y = packbf2(w.z, w.w);
        ((uint2*)Wob)[idx] = p;
    } else if (b < 1027) {                // Wq/Wk/Wv: 1024 float4 each
        const float* W = (b == 1024) ? Wq : (b == 1025) ? Wk : Wv;
        unsigned short* Wb = (b == 1024) ? Wqb : (b == 1025) ? Wkb : Wvb;
        #pragma unroll
        for (int i = 0; i < 4; ++i) {
            int idx = tid + i * 256;
            float4 w = ((const float4*)W)[idx];
            uint2 p; p.x = packbf2(w.x, w.y); p.y = packbf2(w.z, w.w);
            ((uint2*)Wb)[idx] = p;
        }
    } else {                              // Mb: NB*SEQ bf16 entries (1.0 / 0.0)
        #pragma unroll
        for (int i = 0; i < 16; ++i) {
            int idx = tid + i * 256;
            Mb[idx] = mask[idx] ? (unsigned short)0x3F80 : (unsigned short)0;
        }
    }
}

// ---------------------------------------------------------------------------
// Kernel 1: per-head QKV projection.  grid (SEQ/128, NH, 3*NB), block 256.
// Q,K out: [n][h][l][d] bf16 (Q pre-scaled by QSCALE).  V out: [n][h][d][l],
// with MASKED ROWS OF V ZEROED (so flash needs no per-score mask handling:
// numerator excludes masked keys via V=0, denominator via the mask-MFMA).
// ---------------------------------------------------------------------------
__global__ __launch_bounds__(256) void qkv_kernel(
    const float* __restrict__ Qin, const float* __restrict__ Kin,
    const float* __restrict__ Vin,
    const unsigned short* __restrict__ Wqb, const unsigned short* __restrict__ Wkb,
    const unsigned short* __restrict__ Wvb, const float* __restrict__ bq,
    const int* __restrict__ mask,
    unsigned short* __restrict__ Qp, unsigned short* __restrict__ Kp,
    unsigned short* __restrict__ Vtp)
{
    const int lt = blockIdx.x;          // 128-row l tile
    const int h  = blockIdx.y;
    const int tz = blockIdx.z;
    const int t  = tz >> 1, n = tz & 1;

    const float* X; const unsigned short* Wb;
    if (t == 0)      { X = Qin; Wb = Wqb; }
    else if (t == 1) { X = Kin; Wb = Wkb; }
    else             { X = Vin; Wb = Wvb; }

    __shared__ __align__(16) unsigned short sX[128][70];
    __shared__ __align__(16) unsigned short sT[64][136];

    const int tid = threadIdx.x, wave = tid >> 6, lane = tid & 63;
    const int ln = lane & 15, quad = lane >> 4;

    #pragma unroll
    for (int i = 0; i < 8; ++i) {
        int flat = tid + i * 256;
        int r = flat >> 4, c4 = flat & 15;
        float4 xv = *(const float4*)(X + ((size_t)(n * SEQ + lt * 128 + r)) * EMB + h * HD + c4 * 4);
        uint2 xp; xp.x = packbf2(xv.x, xv.y); xp.y = packbf2(xv.z, xv.w);
        *(uint2*)&sX[r][c4 * 4] = xp;
    }
    short8 wf0[4], wf1[4];
    #pragma unroll
    for (int nt = 0; nt < 4; ++nt) {
        wf0[nt] = *(const short8*)(Wb + (nt * 16 + ln) * HD + quad * 8);
        wf1[nt] = *(const short8*)(Wb + (nt * 16 + ln) * HD + 32 + quad * 8);
    }
    __syncthreads();

    f32x4 acc[2][4];
    #pragma unroll
    for (int set = 0; set < 2; ++set) {
        short8 af0 = *(const short8*)&sX[wave * 32 + set * 16 + ln][quad * 8];
        short8 af1 = *(const short8*)&sX[wave * 32 + set * 16 + ln][32 + quad * 8];
        #pragma unroll
        for (int nt = 0; nt < 4; ++nt) {
            f32x4 a = {0.f, 0.f, 0.f, 0.f};
            a = MFMA(af0, wf0[nt], a);
            a = MFMA(af1, wf1[nt], a);
            acc[set][nt] = a;
        }
    }

    if (t == 0) {   // bias then fold softmax scale (incl. log2e)
        #pragma unroll
        for (int nt = 0; nt < 4; ++nt) {
            float bb = bq[nt * 16 + ln];
            #pragma unroll
            for (int set = 0; set < 2; ++set)
                #pragma unroll
                for (int a = 0; a < 4; ++a)
                    acc[set][nt][a] = (acc[set][nt][a] + bb) * QSCALE;
        }
    }

    if (t < 2) {
        unsigned short* Out = (t == 0) ? Qp : Kp;
        #pragma unroll
        for (int set = 0; set < 2; ++set)
            #pragma unroll
            for (int a = 0; a < 4; ++a) {
                size_t row = (size_t)((n * NH + h) * SEQ + lt * 128 + wave * 32 + set * 16 + quad * 4 + a);
                #pragma unroll
                for (int nt = 0; nt < 4; ++nt)
                    Out[row * HD + nt * 16 + ln] = f2bf(acc[set][nt][a]);
            }
    } else {
        // zero masked V rows (l = column of V^T)
        #pragma unroll
        for (int set = 0; set < 2; ++set)
            #pragma unroll
            for (int a = 0; a < 4; ++a) {
                int l = lt * 128 + wave * 32 + set * 16 + quad * 4 + a;
                if (mask[n * SEQ + l] == 0) {
                    #pragma unroll
                    for (int nt = 0; nt < 4; ++nt) acc[set][nt][a] = 0.f;
                }
            }
        #pragma unroll
        for (int set = 0; set < 2; ++set)
            #pragma unroll
            for (int nt = 0; nt < 4; ++nt)
                #pragma unroll
                for (int a = 0; a < 4; ++a)
                    sT[nt * 16 + ln][wave * 32 + set * 16 + quad * 4 + a] = f2bf(acc[set][nt][a]);
        __syncthreads();
        #pragma unroll
        for (int i = 0; i < 4; ++i) {
            int flat = tid + i * 256;
            int r = flat >> 4, c8 = flat & 15;
            *(float4*)(Vtp + ((size_t)((n * NH + h) * HD + r)) * SEQ + lt * 128 + c8 * 8) =
                *(const float4*)&sT[r][c8 * 8];
        }
    }
}

// ---------------------------------------------------------------------------
// Kernel 2: flash attention v11 — v9 geometry + VALU-slim softmax.
// Diagnosis r4/r6: v9 (32q/wave) and v10 (16q/wave) both 77us.  v10 was
// LDS-port-bound (18 b128/kt/wave at 16q -> ~46us of ds_read) and v9 was
// nearly ADDITIVE (LDS 26 + VALU 39 + MFMA 12 ~ 77) at 2 waves/SIMD.
// v11 keeps v9's geometry (best K/V amortization: 20 b128/kt/wave) and cuts
// the VALU term ~45%:
//   - mask folded OUT of the score chain: no md loads, no +md, no fmin.
//     Masked keys are excluded exactly via (a) V rows zeroed in qkv
//     (numerator) and (b) denominator computed by an extra MFMA against a
//     bf16 mask vector: o_l = mfma(P_frag, mask_frag, o_l).  B-frag of the
//     mask is column-independent -> one broadcast 16B load per half-tile.
//   - lsum VALU adds gone; epilogue shuffle-reduce gone (o_l[set][a] is
//     already aligned with o[set][dt][a]'s row).
//   - denominator sums the same bf16 P the numerator uses (rel err ~2e-5).
// Per-quad VALU: 24 -> ~11 (4 exp2 + 2 cvt_pk + addressing).
// grid (NB*NH, SEQ/128), block 256 (4 waves x 32 q-rows).
// ---------------------------------------------------------------------------
__global__ __launch_bounds__(256) void flash_kernel(
    const unsigned short* __restrict__ Qp, const unsigned short* __restrict__ Kp,
    const unsigned short* __restrict__ Vtp, const unsigned short* __restrict__ Mb,
    unsigned short* __restrict__ A /* [n][l][EMB] bf16 */)
{
    const int nh = blockIdx.x;
    const int qt = blockIdx.y;            // 128-row q tile
    const int n  = nh >> 4, h = nh & 15;

    const int tid  = threadIdx.x;
    const int wave = tid >> 6, lane = tid & 63;
    const int ln   = lane & 15, quad = lane >> 4;
    const int ln7  = lane & 7;

    __shared__ __align__(16) unsigned short Kb[2][64 * 64];   // 16 KiB
    __shared__ __align__(16) unsigned short Vb[2][64 * 64];   // 16 KiB
    __shared__ __align__(16) unsigned short sP[4][32 * 64];   // 16 KiB
    unsigned short* sPw = sP[wave];

    // Q B-fragments: wave owns q rows qt*128 + wave*32 + set*16 + ln
    const unsigned short* Qb = Qp + ((size_t)nh * SEQ + qt * 128 + wave * 32) * HD;
    short8 qf[2][2];
    #pragma unroll
    for (int set = 0; set < 2; ++set) {
        qf[set][0] = *(const short8*)(Qb + (set * 16 + ln) * HD + quad * 8);
        qf[set][1] = *(const short8*)(Qb + (set * 16 + ln) * HD + 32 + quad * 8);
    }

    const unsigned short* Kg = Kp  + (size_t)nh * SEQ * HD;
    const unsigned short* Vg = Vtp + (size_t)nh * HD * SEQ;
    const unsigned short* mk = Mb + n * SEQ;

    // staging geometry: each gload16 = 1 KiB = 8 rows of 128B.  Wave w stages
    // rows [16w, 16w+16) of both K and V (2 instrs each).  Source chunk is
    // pre-swizzled: lane l fetches chunk (l&7)^(l>>3) of row (l>>3) so that
    // LDS(row, c) holds global(row, c ^ (row&7)).
    const int r8  = lane >> 3;                       // 0..7
    const int swz = ((lane & 7) ^ r8) << 3;          // shorts within row

    f32x4 o[2][4];
    #pragma unroll
    for (int s2 = 0; s2 < 2; ++s2)
        #pragma unroll
        for (int dt = 0; dt < 4; ++dt) o[s2][dt] = (f32x4){0.f, 0.f, 0.f, 0.f};
    f32x4 ol[2] = {(f32x4){0.f, 0.f, 0.f, 0.f}, (f32x4){0.f, 0.f, 0.f, 0.f}};

    #define STAGE(buf, kt_) do {                                                  \
        const unsigned short* kg_ = Kg + ((size_t)((kt_) * 64 + wave * 16 + r8)) * HD + swz; \
        const unsigned short* vg_ = Vg + ((size_t)(wave * 16 + r8)) * SEQ + (kt_) * 64 + swz; \
        unsigned short* kl_ = &Kb[buf][wave * 16 * 64];                           \
        unsigned short* vl_ = &Vb[buf][wave * 16 * 64];                           \
        gload16(kg_,            kl_);                                             \
        gload16(kg_ + 8 * HD,   kl_ + 8 * 64);                                    \
        gload16(vg_,            vl_);                                             \
        gload16(vg_ + 8 * SEQ,  vl_ + 8 * 64);                                    \
    } while (0)

    STAGE(0, 0);
    __syncthreads();                       // drains vmcnt -> tile 0 ready
    int cur = 0;

    for (int kt = 0; kt < SEQ / 64; ++kt) {
        // bf16 mask fragments for this k-tile (broadcast 16B loads, L1-hot)
        short8 mf0 = *(const short8*)(mk + kt * 64 + quad * 8);
        short8 mf1 = *(const short8*)(mk + kt * 64 + 32 + quad * 8);

        if (kt + 1 < SEQ / 64) STAGE(cur ^ 1, kt + 1);   // async prefetch

        // ---- S^T = K Q^T, exp2, P -> sP (swizzled).  No mask, no clamp,
        //      no scalar lsum: denominator comes from the mask-MFMA below.
        const unsigned short* Kc = Kb[cur];
        #pragma unroll
        for (int nt = 0; nt < 4; ++nt) {
            short8 kf0 = *(const short8*)&Kc[(nt * 16 + ln) * 64 + (((quad)     ^ ln7) << 3)];
            short8 kf1 = *(const short8*)&Kc[(nt * 16 + ln) * 64 + (((quad + 4) ^ ln7) << 3)];
            #pragma unroll
            for (int set = 0; set < 2; ++set) {
                f32x4 z = {0.f, 0.f, 0.f, 0.f};
                z = MFMA(kf0, qf[set][0], z);
                z = MFMA(kf1, qf[set][1], z);
                // S^T C-layout: (key = nt*16+quad*4+a, q = set*16+ln)
                float p0 = EXP2(z[0]);
                float p1 = EXP2(z[1]);
                float p2 = EXP2(z[2]);
                float p3 = EXP2(z[3]);
                uint2 w; w.x = packbf2(p0, p1); w.y = packbf2(p2, p3);
                int prow  = set * 16 + ln;
                int chunk = nt * 2 + (quad >> 1);
                *(uint2*)&sPw[prow * 64 + ((chunk ^ ln7) << 3) + (quad & 1) * 4] = w;
            }
        }
        asm volatile("s_waitcnt lgkmcnt(0)" ::: "memory");   // per-wave P slice

        // ---- O += P V ;  l += P m  (mask-MFMA) ----
        const unsigned short* Vc = Vb[cur];
        short8 pf[2][2];
        #pragma unroll
        for (int set = 0; set < 2; ++set) {
            pf[set][0] = *(const short8*)&sPw[(set * 16 + ln) * 64 + (((quad)     ^ ln7) << 3)];
            pf[set][1] = *(const short8*)&sPw[(set * 16 + ln) * 64 + (((quad + 4) ^ ln7) << 3)];
        }
        #pragma unroll
        for (int set = 0; set < 2; ++set) {
            ol[set] = MFMA(pf[set][0], mf0, ol[set]);
            ol[set] = MFMA(pf[set][1], mf1, ol[set]);
        }
        #pragma unroll
        for (int dt = 0; dt < 4; ++dt) {
            short8 vf0 = *(const short8*)&Vc[(dt * 16 + ln) * 64 + (((quad)     ^ ln7) << 3)];
            short8 vf1 = *(const short8*)&Vc[(dt * 16 + ln) * 64 + (((quad + 4) ^ ln7) << 3)];
            #pragma unroll
            for (int set = 0; set < 2; ++set) {
                o[set][dt] = MFMA(pf[set][0], vf0, o[set][dt]);
                o[set][dt] = MFMA(pf[set][1], vf1, o[set][dt]);
            }
        }

        __syncthreads();   // implicit vmcnt(0)+lgkmcnt(0): prefetch landed, all reads done
        cur ^= 1;
    }
    #undef STAGE

    // ---- normalize own rows and write (ol[set][a] aligns with o[set][dt][a]) ----
    #pragma unroll
    for (int set = 0; set < 2; ++set)
        #pragma unroll
        for (int a = 0; a < 4; ++a) {
            float inv = 1.0f / ol[set][a];
            size_t row = (size_t)(n * SEQ + qt * 128 + wave * 32 + set * 16 + quad * 4 + a);
            #pragma unroll
            for (int dt = 0; dt < 4; ++dt)
                A[row * EMB + h * HD + dt * 16 + ln] = f2bf(o[set][dt][a] * inv);
        }
}

// ---------------------------------------------------------------------------
// Kernel 3: out = A @ Wo^T + bo, 128x128 tile (m93 structure).
// grid (EMB/128, NB*SEQ/128), block 256 (2x2 waves of 64x64).
// ---------------------------------------------------------------------------
__global__ __launch_bounds__(256) void outproj_kernel(
    const unsigned short* __restrict__ A, const unsigned short* __restrict__ Wob,
    const float* __restrict__ bo, float* __restrict__ Out)
{
    const int ct = blockIdx.x;   // 128-col tile
    const int rt = blockIdx.y;   // 128-row tile

    const int tid  = threadIdx.x;
    const int wave = tid >> 6, lane = tid & 63;
    const int ln   = lane & 15, quad = lane >> 4;
    const int wm   = wave >> 1, wn = wave & 1;

    __shared__ __align__(16) unsigned short sA[128][72];
    __shared__ __align__(16) unsigned short sB[128][72];

    f32x4 acc[4][4];
    #pragma unroll
    for (int i = 0; i < 4; ++i)
        #pragma unroll
        for (int j = 0; j < 4; ++j) acc[i][j] = (f32x4){0.f, 0.f, 0.f, 0.f};

    for (int kc = 0; kc < EMB / 64; ++kc) {
        __syncthreads();
        #pragma unroll
        for (int i = 0; i < 4; ++i) {
            int flat = tid + i * 256;          // 0..1023, 8-bf16 groups
            int r = flat >> 3, c8 = flat & 7;
            *(float4*)&sA[r][c8 * 8] =
                *(const float4*)(A + (size_t)(rt * 128 + r) * EMB + kc * 64 + c8 * 8);
            *(float4*)&sB[r][c8 * 8] =
                *(const float4*)(Wob + (size_t)(ct * 128 + r) * EMB + kc * 64 + c8 * 8);
        }
        __syncthreads();

        #pragma unroll
        for (int ks = 0; ks < 2; ++ks) {
            short8 af[4], bf[4];
            #pragma unroll
            for (int i = 0; i < 4; ++i)
                af[i] = *(const short8*)&sA[wm * 64 + i * 16 + ln][ks * 32 + quad * 8];
            #pragma unroll
            for (int j = 0; j < 4; ++j)
                bf[j] = *(const short8*)&sB[wn * 64 + j * 16 + ln][ks * 32 + quad * 8];
            #pragma unroll
            for (int i = 0; i < 4; ++i)
                #pragma unroll
                for (int j = 0; j < 4; ++j)
                    acc[i][j] = MFMA(af[i], bf[j], acc[i][j]);
        }
    }

    #pragma unroll
    for (int j = 0; j < 4; ++j) {
        int col = ct * 128 + wn * 64 + j * 16 + ln;
        float bb = bo[col];
        #pragma unroll
        for (int i = 0; i < 4; ++i)
            #pragma unroll
            for (int a = 0; a < 4; ++a) {
                size_t row = (size_t)(rt * 128 + wm * 64 + i * 16 + quad * 4 + a);
                Out[row * EMB + col] = acc[i][j][a] + bb;
            }
    }
}

// ---------------------------------------------------------------------------
extern "C" void kernel_launch(void* const* d_in, const int* in_sizes, int n_in,
                              void* d_out, int out_size, void* d_ws, size_t ws_size,
                              hipStream_t stream) {
    const float* values = (const float*)d_in[0];
    const float* key_   = (const float*)d_in[1];
    const float* query  = (const float*)d_in[2];
    const int*   mask   = (const int*)d_in[3];
    const float* Wv     = (const float*)d_in[4];
    const float* Wk     = (const float*)d_in[5];
    const float* Wq     = (const float*)d_in[6];
    const float* bq     = (const float*)d_in[7];
    const float* Wo     = (const float*)d_in[8];
    const float* bo     = (const float*)d_in[9];
    float* out = (float*)d_out;

    const size_t NHLD = (size_t)NB * NH * SEQ * HD;   // 4,194,304

    unsigned short* ws = (unsigned short*)d_ws;
    unsigned short* Qp    = ws;
    unsigned short* Kp    = ws + NHLD;
    unsigned short* Vtp   = ws + 2 * NHLD;
    unsigned short* Aattn = ws + 3 * NHLD;
    unsigned short* Wob   = ws + 4 * NHLD;                  // EMB*EMB
    unsigned short* Wqb   = Wob + (size_t)EMB * EMB;
    unsigned short* Wkb   = Wqb + HD * HD;
    unsigned short* Wvb   = Wkb + HD * HD;
    unsigned short* Mb    = Wvb + HD * HD;                  // NB*SEQ bf16 mask

    cvt_kernel<<<dim3(1028), 256, 0, stream>>>(
        Wo, Wq, Wk, Wv, mask, Wob, Wqb, Wkb, Wvb, Mb);
    qkv_kernel<<<dim3(SEQ / 128, NH, 3 * NB), 256, 0, stream>>>(
        query, key_, values, Wqb, Wkb, Wvb, bq, mask, Qp, Kp, Vtp);
    flash_kernel<<<dim3(NB * NH, SEQ / 128), 256, 0, stream>>>(
        Qp, Kp, Vtp, Mb, Aattn);
    outproj_kernel<<<dim3(EMB / 128, NB * SEQ / 128), 256, 0, stream>>>(
        Aattn, Wob, bo, out);
}